// Round 11
// baseline (126.221 us; speedup 1.0000x reference)
//
#include <hip/hip_runtime.h>
#include <hip/hip_bf16.h>

#define M_ 501
#define T_ 512
#define DT_ 0.01f

typedef __attribute__((ext_vector_type(8))) __bf16 bf16x8;
typedef __attribute__((ext_vector_type(4))) float f32x4;

static __device__ __forceinline__ unsigned int pack2(float a, float b) {
    __hip_bfloat16 ha = __float2bfloat16(a);
    __hip_bfloat16 hb = __float2bfloat16(b);
    unsigned short ua = __builtin_bit_cast(unsigned short, ha);
    unsigned short ub = __builtin_bit_cast(unsigned short, hb);
    return (unsigned int)ua | ((unsigned int)ub << 16);
}

// ---------------- P2: W1comb (1024 x 384) pre-swizzled into MFMA fragment order
// [((kg*24 + nt)*64 + lane)*8 + e] : k = kg*32 + (lane>>4)*8 + e, n = nt*16 + (lane&15)
__global__ void build_w(const float* __restrict__ Ew1, const float* __restrict__ bw1,
                        const float* __restrict__ nw1, __hip_bfloat16* __restrict__ Wswz) {
    int idx = blockIdx.x * 256 + threadIdx.x;       // total 32*24*64*8 = 393216
    if (idx >= 32 * 24 * 64 * 8) return;
    int e  = idx & 7;
    int l  = (idx >> 3) & 63;
    int t  = idx >> 9;
    int nt = t % 24, k0 = t / 24;
    int k  = k0 * 32 + ((l >> 4) << 3) + e;
    int n  = nt * 16 + (l & 15);
    float v = 0.f;
    if (n < 128)      { if (k < 2*M_)             v = Ew1[k * 128 + n]; }
    else if (n < 256) { if (k < 2*M_)             v = bw1[k * 128 + (n - 128)]; }
    else              { if (k >= M_ && k < 2*M_)  v = nw1[(k - M_) * 128 + (n - 256)]; }
    Wswz[idx] = __float2bfloat16(v);
}

// ---------------- Fused GEMM, 32 rows/block, 4 waves, 3 blocks/CU ------------
// 256 thr, grid 1024. Chunk = 128 k-cols; sA[2][32][128] bf16 = 2 x 8KB, XOR
// swizzled (byte ^= (row&7)<<4). LDS ~20KB/block -> 3 blocks/CU (12 waves/CU):
// barriers sync only 4 waves; other blocks' waves hide W/L2 + staging latency.
// Per wave: 2 mi x 6 nt, W loaded inline (TLP hides it). Hidden on reg axis.
__global__ __launch_bounds__(256, 3) void mlp_gemm4(
    const float* __restrict__ E, const float* __restrict__ nu,
    const __hip_bfloat16* __restrict__ Wswz,
    const float* __restrict__ Eb1, const float* __restrict__ bb1, const float* __restrict__ nb1,
    const float* __restrict__ Ew2, const float* __restrict__ bw2, const float* __restrict__ nw2,
    const float* __restrict__ Eb2, const float* __restrict__ bb2, const float* __restrict__ nb2,
    float* __restrict__ Emod, float* __restrict__ nuv, float* __restrict__ beta, int B)
{
    const int tid = threadIdx.x;
    const int wid = tid >> 6, l = tid & 63;
    const int c = l & 15, g = l >> 4;
    const int brow = blockIdx.x * 32;

    __shared__ __align__(16) unsigned char sAraw[2][32 * 256];    // 16 KB
    __shared__ float cb1[384], cw2[384];
    __shared__ float lds_s[3][32];

    for (int n = tid; n < 384; n += 256) {
        cb1[n] = (n < 128) ? Eb1[n] : (n < 256) ? bb1[n - 128] : nb1[n - 256];
        cw2[n] = (n < 128) ? Ew2[n] : (n < 256) ? bw2[n - 128] : nw2[n - 256];
    }
    if (tid < 96) ((float*)lds_s)[tid] = 0.f;

    // ---- staging machinery (2 items/thread, 8 elems each) ----
    f32x4 q[6]; int ofs[2];
    auto stage_load = [&](int ch) {
        #pragma unroll
        for (int j = 0; j < 2; ++j) {
            int idx = tid + j * 256;                 // 0..511
            int r = idx >> 4, u = idx & 15;
            int cu = ch * 16 + u;
            size_t rb = (size_t)(brow + r) * M_;
            bool slow = (cu == 62) | (cu >= 124);
            if (!slow) {
                const float* src = (cu < 62) ? E : nu;
                int off = (cu < 62) ? cu * 8 : cu * 8 - M_;
                size_t s = rb + (size_t)off;
                ofs[j] = (int)(s & 3);
                const f32x4* p = (const f32x4*)(src + (s & ~(size_t)3));
                q[3*j] = p[0]; q[3*j+1] = p[1]; q[3*j+2] = p[2];
            } else {
                int kb = cu * 8;
                auto ldx = [&](int k) -> float {
                    return (k < M_) ? E[rb + k] : ((k < 2 * M_) ? nu[rb + k - M_] : 0.f);
                };
                q[3*j]   = (f32x4){ldx(kb+0), ldx(kb+1), ldx(kb+2), ldx(kb+3)};
                q[3*j+1] = (f32x4){ldx(kb+4), ldx(kb+5), ldx(kb+6), ldx(kb+7)};
                q[3*j+2] = (f32x4){0.f, 0.f, 0.f, 0.f};
                ofs[j] = 0;
            }
        }
    };
    auto stage_finish = [&](int nbuf) {
        #pragma unroll
        for (int j = 0; j < 2; ++j) {
            // Pin at first use: keeps selects un-foldable into scalar loads,
            // and the vmcnt wait lands after the chunk's MFMAs.
            asm volatile("" : "+v"(q[3*j]), "+v"(q[3*j+1]), "+v"(q[3*j+2]));
            int idx = tid + j * 256;
            int r = idx >> 4, u = idx & 15;
            float g0 = q[3*j][0],   g1 = q[3*j][1],   g2 = q[3*j][2],   g3 = q[3*j][3],
                  g4 = q[3*j+1][0], g5 = q[3*j+1][1], g6 = q[3*j+1][2], g7 = q[3*j+1][3],
                  g8 = q[3*j+2][0], g9 = q[3*j+2][1], g10 = q[3*j+2][2];
            const bool o2 = (ofs[j] & 2) != 0, o1 = (ofs[j] & 1) != 0;
            float u0 = o2?g2:g0, u1 = o2?g3:g1, u2 = o2?g4:g2, u3 = o2?g5:g3,
                  u4 = o2?g6:g4, u5 = o2?g7:g5, u6 = o2?g8:g6, u7 = o2?g9:g7,
                  u8 = o2?g10:g8;
            float f0 = o1?u1:u0, f1 = o1?u2:u1, f2 = o1?u3:u2, f3 = o1?u4:u3,
                  f4 = o1?u5:u4, f5 = o1?u6:u5, f6 = o1?u7:u6, f7 = o1?u8:u7;
            uint4 vv;
            vv.x = pack2(f0, f1); vv.y = pack2(f2, f3);
            vv.z = pack2(f4, f5); vv.w = pack2(f6, f7);
            unsigned bo = ((unsigned)r << 8) + ((((unsigned)u) << 4) ^ (((unsigned)(r & 7)) << 4));
            *(uint4*)(sAraw[nbuf] + bo) = vv;
        }
    };

    const bf16x8* wbase = (const bf16x8*)Wswz;

    f32x4 acc[2][6];
    #pragma unroll
    for (int mi = 0; mi < 2; mi++)
        #pragma unroll
        for (int nt = 0; nt < 6; nt++) acc[mi][nt] = (f32x4){0.f, 0.f, 0.f, 0.f};

    // ---- prologue ----
    stage_load(0);
    stage_finish(0);
    __syncthreads();

    // ---- chunk loop ----
    for (int ch = 0; ch < 8; ++ch) {
        const int buf = ch & 1;
        if (ch < 7) stage_load(ch + 1);              // issue-early (T14)
        #pragma unroll
        for (int kk = 0; kk < 4; ++kk) {
            const int kg = ch * 4 + kk;
            bf16x8 w[6];
            #pragma unroll
            for (int nt = 0; nt < 6; ++nt)
                w[nt] = wbase[(size_t)(kg * 24 + wid * 6 + nt) * 64 + l];
            bf16x8 af[2];
            #pragma unroll
            for (int mi = 0; mi < 2; ++mi) {
                int row = c + mi * 16;
                unsigned bo = ((unsigned)row << 8) +
                    ((((unsigned)kk << 6) + ((unsigned)g << 4)) ^ (((unsigned)(row & 7)) << 4));
                af[mi] = *(const bf16x8*)(sAraw[buf] + bo);
            }
            #pragma unroll
            for (int nt = 0; nt < 6; ++nt)
                #pragma unroll
                for (int mi = 0; mi < 2; ++mi)
                    acc[mi][nt] = __builtin_amdgcn_mfma_f32_16x16x32_bf16(w[nt], af[mi], acc[mi][nt], 0, 0, 0);
        }
        if (ch < 7) stage_finish(buf ^ 1);           // write-late
        __syncthreads();
    }

    // ---- epilogue: hidden-units on reg axis -> cheap reduce ----
    #pragma unroll
    for (int mi = 0; mi < 2; ++mi) {
        float s0 = 0.f, s1 = 0.f, s2 = 0.f;
        #pragma unroll
        for (int nt = 0; nt < 6; ++nt) {
            int gnt = wid * 6 + nt;
            int m = gnt >> 3;                        // 0:E 1:beta 2:nu
            float p = 0.f;
            #pragma unroll
            for (int r = 0; r < 4; ++r) {
                int nidx = gnt * 16 + g * 4 + r;
                float x = acc[mi][nt][r] + cb1[nidx];
                float h = fmaxf(x, 0.f) + __logf(1.f + __expf(-fabsf(x)));
                p += h * cw2[nidx];
            }
            if (m == 0) s0 += p; else if (m == 1) s1 += p; else s2 += p;
        }
        const int m_first = (wid * 6) >> 3, m_last = (wid * 6 + 5) >> 3;
        auto red = [&](float v, int m) {
            v += __shfl_xor(v, 16);
            v += __shfl_xor(v, 32);
            if (l < 16) atomicAdd(&lds_s[m][mi * 16 + l], v);
        };
        if (m_first == 0) red(s0, 0);
        if (m_first <= 1 && m_last >= 1) red(s1, 1);
        if (m_last == 2) red(s2, 2);
    }
    __syncthreads();

    if (tid < 32) {
        int b = brow + tid;
        float s0 = lds_s[0][tid], s1 = lds_s[1][tid], s2 = lds_s[2][tid];
        Emod[b] = __expf(s0 + Eb2[0]);
        float mb = s1 + bb2[0];
        beta[b]  = mb * mb * (1.f / 40000.f);
        float mn = s2 + nb2[0];
        nuv[b]   = __expf(mn * mn * (1.f / 40000.f));
    }
}

// ---------------- Scan: one wave per row b, lane i owns t in [8i, 8i+8) ------
__global__ __launch_bounds__(256) void scan_k(
    const float* __restrict__ e, const float* __restrict__ ed,
    const float* __restrict__ Emod, const float* __restrict__ nuv, const float* __restrict__ beta,
    float* __restrict__ stress, float* __restrict__ xiout)
{
    int lane = threadIdx.x & 63;
    int b = blockIdx.x * 4 + (threadIdx.x >> 6);
    float Em = Emod[b], nv = nuv[b], bt = beta[b];
    float cc = DT_ * bt;
    float a  = 1.f - cc;

    size_t base = (size_t)b * T_ + (size_t)lane * 8;
    float4 e0 = *(const float4*)(e + base),  e1 = *(const float4*)(e + base + 4);
    float4 d0 = *(const float4*)(ed + base), d1 = *(const float4*)(ed + base + 4);
    float ev[8] = {e0.x, e0.y, e0.z, e0.w, e1.x, e1.y, e1.z, e1.w};
    float dv[8] = {d0.x, d0.y, d0.z, d0.w, d1.x, d1.y, d1.z, d1.w};

    float S = 0.f;
    #pragma unroll
    for (int j = 0; j < 8; j++) S = a * S + ev[j];
    float a2 = a * a, a4 = a2 * a2, A = a4 * a4;

    #pragma unroll
    for (int d = 1; d < 64; d <<= 1) {
        float Su = __shfl_up(S, d);
        float Au = __shfl_up(A, d);
        if (lane >= d) { S = Su * A + S; A = Au * A; }
    }
    float Sp = __shfl_up(S, 1);
    float xi = (lane == 0) ? 0.f : cc * Sp;

    float st[8], xo[8];
    #pragma unroll
    for (int j = 0; j < 8; j++) {
        xo[j] = xi;
        float qd = ev[j] - xi;
        st[j] = Em * ev[j] + qd + nv * dv[j];
        xi = xi + cc * qd;
    }
    *(float4*)(stress + base)     = (float4){st[0], st[1], st[2], st[3]};
    *(float4*)(stress + base + 4) = (float4){st[4], st[5], st[6], st[7]};
    *(float4*)(xiout + base)      = (float4){xo[0], xo[1], xo[2], xo[3]};
    *(float4*)(xiout + base + 4)  = (float4){xo[4], xo[5], xo[6], xo[7]};
}

extern "C" void kernel_launch(void* const* d_in, const int* in_sizes, int n_in,
                              void* d_out, int out_size, void* d_ws, size_t ws_size,
                              hipStream_t stream) {
    const float* e   = (const float*)d_in[0];
    const float* ed  = (const float*)d_in[1];
    const float* E   = (const float*)d_in[2];
    const float* nu  = (const float*)d_in[3];
    const float* Ew1 = (const float*)d_in[4];
    const float* Eb1 = (const float*)d_in[5];
    const float* Ew2 = (const float*)d_in[6];
    const float* Eb2 = (const float*)d_in[7];
    const float* nw1 = (const float*)d_in[8];
    const float* nb1 = (const float*)d_in[9];
    const float* nw2 = (const float*)d_in[10];
    const float* nb2 = (const float*)d_in[11];
    const float* bw1 = (const float*)d_in[12];
    const float* bb1 = (const float*)d_in[13];
    const float* bw2 = (const float*)d_in[14];
    const float* bb2 = (const float*)d_in[15];

    int B = in_sizes[2] / M_;                       // 32768

    char* ws = (char*)d_ws;
    __hip_bfloat16* Wswz = (__hip_bfloat16*)ws;                                   // 786432 bytes
    float* Emod = (float*)(ws + (size_t)1024 * 384 * 2);
    float* nuv  = Emod + B;
    float* beta = nuv + B;

    build_w<<<(1024 * 384 + 255) / 256, 256, 0, stream>>>(Ew1, bw1, nw1, Wswz);
    mlp_gemm4<<<B / 32, 256, 0, stream>>>(E, nu, Wswz, Eb1, bb1, nb1,
                                          Ew2, bw2, nw2, Eb2, bb2, nb2,
                                          Emod, nuv, beta, B);
    float* stress = (float*)d_out;
    float* xiout  = stress + (size_t)B * T_;
    scan_k<<<B / 4, 256, 0, stream>>>(e, ed, Emod, nuv, beta, stress, xiout);
}

// Round 12
// 113.197 us; speedup vs baseline: 1.1151x; 1.1151x over previous
//
#include <hip/hip_runtime.h>
#include <hip/hip_bf16.h>

#define M_ 501
#define T_ 512
#define DT_ 0.01f

typedef __attribute__((ext_vector_type(8))) __bf16 bf16x8;
typedef __attribute__((ext_vector_type(4))) float f32x4;

static __device__ __forceinline__ unsigned int pack2(float a, float b) {
    __hip_bfloat16 ha = __float2bfloat16(a);
    __hip_bfloat16 hb = __float2bfloat16(b);
    unsigned short ua = __builtin_bit_cast(unsigned short, ha);
    unsigned short ub = __builtin_bit_cast(unsigned short, hb);
    return (unsigned int)ua | ((unsigned int)ub << 16);
}

// ---------------- P2: W1comb (1024 x 384) pre-swizzled into MFMA fragment order
// [((kg*24 + nt)*64 + lane)*8 + e] : k = kg*32 + (lane>>4)*8 + e, n = nt*16 + (lane&15)
__global__ void build_w(const float* __restrict__ Ew1, const float* __restrict__ bw1,
                        const float* __restrict__ nw1, __hip_bfloat16* __restrict__ Wswz) {
    int idx = blockIdx.x * 256 + threadIdx.x;       // total 32*24*64*8 = 393216
    if (idx >= 32 * 24 * 64 * 8) return;
    int e  = idx & 7;
    int l  = (idx >> 3) & 63;
    int t  = idx >> 9;
    int nt = t % 24, k0 = t / 24;
    int k  = k0 * 32 + ((l >> 4) << 3) + e;
    int n  = nt * 16 + (l & 15);
    float v = 0.f;
    if (n < 128)      { if (k < 2*M_)             v = Ew1[k * 128 + n]; }
    else if (n < 256) { if (k < 2*M_)             v = bw1[k * 128 + (n - 128)]; }
    else              { if (k >= M_ && k < 2*M_)  v = nw1[(k - M_) * 128 + (n - 256)]; }
    Wswz[idx] = __float2bfloat16(v);
}

// ---------------- Fused GEMM, 64 rows/block, BK=64, grid 512 = 2 blocks/CU ---
// 512 thr (8 waves). sA[2][64][64] bf16 = 2 x 16KB (row stride 128B), XOR
// swizzled (byte ^= (row&7)<<4). LDS ~21KB -> 2 blocks/CU by grid; VGPR target
// <=128 (q[3] staging, acc 48) -> 4 waves/SIMD. Per kg: 3 W-loads : 12 MFMA
// (R8 ratio), W prefetched 1-kg deep (wa/wb). T14: stage issue at chunk top,
// finish (select+pack+ds_write) after MFMAs. Hidden units on reg axis.
__global__ __launch_bounds__(512, 2) void mlp_gemm5(
    const float* __restrict__ E, const float* __restrict__ nu,
    const __hip_bfloat16* __restrict__ Wswz,
    const float* __restrict__ Eb1, const float* __restrict__ bb1, const float* __restrict__ nb1,
    const float* __restrict__ Ew2, const float* __restrict__ bw2, const float* __restrict__ nw2,
    const float* __restrict__ Eb2, const float* __restrict__ bb2, const float* __restrict__ nb2,
    float* __restrict__ Emod, float* __restrict__ nuv, float* __restrict__ beta, int B)
{
    const int tid = threadIdx.x;
    const int wid = tid >> 6, l = tid & 63;
    const int c = l & 15, g = l >> 4;
    const int brow = blockIdx.x * 64;

    __shared__ __align__(16) unsigned char sAraw[2][64 * 128];    // 16 KB
    __shared__ float cb1[384], cw2[384];
    __shared__ float lds_s[3][64];

    if (tid < 384) {
        int n = tid;
        cb1[n] = (n < 128) ? Eb1[n] : (n < 256) ? bb1[n - 128] : nb1[n - 256];
        cw2[n] = (n < 128) ? Ew2[n] : (n < 256) ? bw2[n - 128] : nw2[n - 256];
    }
    if (tid < 192) ((float*)lds_s)[tid] = 0.f;

    // ---- staging machinery: 1 item/thread/chunk (8 elems) ----
    f32x4 q0, q1, q2; int ofs;
    const int sr = tid >> 3, su = tid & 7;           // row 0..63, col-octet 0..7
    const size_t rb = (size_t)(brow + sr) * M_;
    auto stage_load = [&](int ch) {
        int cu = ch * 8 + su;
        bool slow = (cu == 62) | (cu >= 124);
        if (!slow) {
            const float* src = (cu < 62) ? E : nu;
            int off = (cu < 62) ? cu * 8 : cu * 8 - M_;
            size_t s = rb + (size_t)off;
            ofs = (int)(s & 3);
            const f32x4* p = (const f32x4*)(src + (s & ~(size_t)3));
            q0 = p[0]; q1 = p[1]; q2 = p[2];
        } else {
            int kb = cu * 8;
            auto ldx = [&](int k) -> float {
                return (k < M_) ? E[rb + k] : ((k < 2 * M_) ? nu[rb + k - M_] : 0.f);
            };
            q0 = (f32x4){ldx(kb+0), ldx(kb+1), ldx(kb+2), ldx(kb+3)};
            q1 = (f32x4){ldx(kb+4), ldx(kb+5), ldx(kb+6), ldx(kb+7)};
            q2 = (f32x4){0.f, 0.f, 0.f, 0.f};
            ofs = 0;
        }
    };
    auto stage_finish = [&](int nbuf) {
        // Pin at first use: keeps selects un-foldable into scalar loads; the
        // vmcnt wait lands here, after the chunk's MFMAs.
        asm volatile("" : "+v"(q0), "+v"(q1), "+v"(q2));
        float g0=q0[0], g1=q0[1], g2=q0[2], g3=q0[3],
              g4=q1[0], g5=q1[1], g6=q1[2], g7=q1[3],
              g8=q2[0], g9=q2[1], g10=q2[2];
        const bool o2 = (ofs & 2) != 0, o1 = (ofs & 1) != 0;
        float u0 = o2?g2:g0, u1 = o2?g3:g1, u2 = o2?g4:g2, u3 = o2?g5:g3,
              u4 = o2?g6:g4, u5 = o2?g7:g5, u6 = o2?g8:g6, u7 = o2?g9:g7,
              u8 = o2?g10:g8;
        float f0 = o1?u1:u0, f1 = o1?u2:u1, f2 = o1?u3:u2, f3 = o1?u4:u3,
              f4 = o1?u5:u4, f5 = o1?u6:u5, f6 = o1?u7:u6, f7 = o1?u8:u7;
        uint4 vv;
        vv.x = pack2(f0, f1); vv.y = pack2(f2, f3);
        vv.z = pack2(f4, f5); vv.w = pack2(f6, f7);
        unsigned bo = ((unsigned)sr << 7) + ((((unsigned)su) << 4) ^ (((unsigned)(sr & 7)) << 4));
        *(uint4*)(sAraw[nbuf] + bo) = vv;
    };

    const bf16x8* wbase = (const bf16x8*)Wswz;
    auto loadW3 = [&](bf16x8 (&w)[3], int kg) {
        #pragma unroll
        for (int nt = 0; nt < 3; ++nt)
            w[nt] = wbase[(size_t)(kg * 24 + wid * 3 + nt) * 64 + l];
    };

    f32x4 acc[4][3];
    #pragma unroll
    for (int mi = 0; mi < 4; mi++)
        #pragma unroll
        for (int nt = 0; nt < 3; nt++) acc[mi][nt] = (f32x4){0.f, 0.f, 0.f, 0.f};
    bf16x8 wa[3], wb[3], af[4];

    auto readAF = [&](int buf, int kk) {
        #pragma unroll
        for (int mi = 0; mi < 4; ++mi) {
            int row = c + mi * 16;
            unsigned bo = ((unsigned)row << 7) +
                ((((unsigned)kk << 6) + ((unsigned)g << 4)) ^ (((unsigned)(row & 7)) << 4));
            af[mi] = *(const bf16x8*)(sAraw[buf] + bo);
        }
    };
    auto M12 = [&](bf16x8 (&w)[3]) {
        #pragma unroll
        for (int nt = 0; nt < 3; ++nt)
            #pragma unroll
            for (int mi = 0; mi < 4; ++mi)
                acc[mi][nt] = __builtin_amdgcn_mfma_f32_16x16x32_bf16(w[nt], af[mi], acc[mi][nt], 0, 0, 0);
    };

    // ---- prologue ----
    stage_load(0);
    stage_finish(0);
    __syncthreads();

    // ---- chunk loop: 16 chunks of BK=64 (2 kg each) ----
    for (int ch = 0; ch < 16; ++ch) {
        const int buf = ch & 1;
        if (ch < 15) stage_load(ch + 1);             // issue-early (T14)
        const int kg = ch * 2;
        loadW3(wa, kg + 0);
        loadW3(wb, kg + 1);
        readAF(buf, 0); M12(wa);
        readAF(buf, 1); M12(wb);
        if (ch < 15) stage_finish(buf ^ 1);          // write-late (vmcnt lands here)
        __syncthreads();
    }

    // ---- epilogue: hidden-units on reg axis -> cheap reduce ----
    float bv[12], wv[12];
    #pragma unroll
    for (int nt = 0; nt < 3; ++nt)
        #pragma unroll
        for (int r = 0; r < 4; ++r) {
            int nidx = (wid * 3 + nt) * 16 + g * 4 + r;
            bv[nt * 4 + r] = cb1[nidx];
            wv[nt * 4 + r] = cw2[nidx];
        }
    const int m_first = (wid * 3) >> 3, m_last = (wid * 3 + 2) >> 3;

    #pragma unroll
    for (int mi = 0; mi < 4; ++mi) {
        float s0 = 0.f, s1 = 0.f, s2 = 0.f;
        #pragma unroll
        for (int nt = 0; nt < 3; ++nt) {
            float p = 0.f;
            #pragma unroll
            for (int r = 0; r < 4; ++r) {
                float x = acc[mi][nt][r] + bv[nt * 4 + r];
                float h = fmaxf(x, 0.f) + __logf(1.f + __expf(-fabsf(x)));
                p += h * wv[nt * 4 + r];
            }
            int m = (wid * 3 + nt) >> 3;
            if (m == 0) s0 += p; else if (m == 1) s1 += p; else s2 += p;
        }
        auto red = [&](float v, int m) {
            v += __shfl_xor(v, 16);
            v += __shfl_xor(v, 32);
            if (l < 16) atomicAdd(&lds_s[m][mi * 16 + l], v);
        };
        if (m_first == 0) red(s0, 0);
        if (m_first <= 1 && m_last >= 1) red(s1, 1);
        if (m_last == 2) red(s2, 2);
    }
    __syncthreads();

    if (tid < 64) {
        int b = brow + tid;
        float s0 = lds_s[0][tid], s1 = lds_s[1][tid], s2 = lds_s[2][tid];
        Emod[b] = __expf(s0 + Eb2[0]);
        float mb = s1 + bb2[0];
        beta[b]  = mb * mb * (1.f / 40000.f);
        float mn = s2 + nb2[0];
        nuv[b]   = __expf(mn * mn * (1.f / 40000.f));
    }
}

// ---------------- Scan: one wave per row b, lane i owns t in [8i, 8i+8) ------
__global__ __launch_bounds__(256) void scan_k(
    const float* __restrict__ e, const float* __restrict__ ed,
    const float* __restrict__ Emod, const float* __restrict__ nuv, const float* __restrict__ beta,
    float* __restrict__ stress, float* __restrict__ xiout)
{
    int lane = threadIdx.x & 63;
    int b = blockIdx.x * 4 + (threadIdx.x >> 6);
    float Em = Emod[b], nv = nuv[b], bt = beta[b];
    float cc = DT_ * bt;
    float a  = 1.f - cc;

    size_t base = (size_t)b * T_ + (size_t)lane * 8;
    float4 e0 = *(const float4*)(e + base),  e1 = *(const float4*)(e + base + 4);
    float4 d0 = *(const float4*)(ed + base), d1 = *(const float4*)(ed + base + 4);
    float ev[8] = {e0.x, e0.y, e0.z, e0.w, e1.x, e1.y, e1.z, e1.w};
    float dv[8] = {d0.x, d0.y, d0.z, d0.w, d1.x, d1.y, d1.z, d1.w};

    float S = 0.f;
    #pragma unroll
    for (int j = 0; j < 8; j++) S = a * S + ev[j];
    float a2 = a * a, a4 = a2 * a2, A = a4 * a4;

    #pragma unroll
    for (int d = 1; d < 64; d <<= 1) {
        float Su = __shfl_up(S, d);
        float Au = __shfl_up(A, d);
        if (lane >= d) { S = Su * A + S; A = Au * A; }
    }
    float Sp = __shfl_up(S, 1);
    float xi = (lane == 0) ? 0.f : cc * Sp;

    float st[8], xo[8];
    #pragma unroll
    for (int j = 0; j < 8; j++) {
        xo[j] = xi;
        float qd = ev[j] - xi;
        st[j] = Em * ev[j] + qd + nv * dv[j];
        xi = xi + cc * qd;
    }
    *(float4*)(stress + base)     = (float4){st[0], st[1], st[2], st[3]};
    *(float4*)(stress + base + 4) = (float4){st[4], st[5], st[6], st[7]};
    *(float4*)(xiout + base)      = (float4){xo[0], xo[1], xo[2], xo[3]};
    *(float4*)(xiout + base + 4)  = (float4){xo[4], xo[5], xo[6], xo[7]};
}

extern "C" void kernel_launch(void* const* d_in, const int* in_sizes, int n_in,
                              void* d_out, int out_size, void* d_ws, size_t ws_size,
                              hipStream_t stream) {
    const float* e   = (const float*)d_in[0];
    const float* ed  = (const float*)d_in[1];
    const float* E   = (const float*)d_in[2];
    const float* nu  = (const float*)d_in[3];
    const float* Ew1 = (const float*)d_in[4];
    const float* Eb1 = (const float*)d_in[5];
    const float* Ew2 = (const float*)d_in[6];
    const float* Eb2 = (const float*)d_in[7];
    const float* nw1 = (const float*)d_in[8];
    const float* nb1 = (const float*)d_in[9];
    const float* nw2 = (const float*)d_in[10];
    const float* nb2 = (const float*)d_in[11];
    const float* bw1 = (const float*)d_in[12];
    const float* bb1 = (const float*)d_in[13];
    const float* bw2 = (const float*)d_in[14];
    const float* bb2 = (const float*)d_in[15];

    int B = in_sizes[2] / M_;                       // 32768

    char* ws = (char*)d_ws;
    __hip_bfloat16* Wswz = (__hip_bfloat16*)ws;                                   // 786432 bytes
    float* Emod = (float*)(ws + (size_t)1024 * 384 * 2);
    float* nuv  = Emod + B;
    float* beta = nuv + B;

    build_w<<<(1024 * 384 + 255) / 256, 256, 0, stream>>>(Ew1, bw1, nw1, Wswz);
    mlp_gemm5<<<B / 64, 512, 0, stream>>>(E, nu, Wswz, Eb1, bb1, nb1,
                                          Ew2, bw2, nw2, Eb2, bb2, nb2,
                                          Emod, nuv, beta, B);
    float* stress = (float*)d_out;
    float* xiout  = stress + (size_t)B * T_;
    scan_k<<<B / 4, 256, 0, stream>>>(e, ed, Emod, nuv, beta, stress, xiout);
}

// Round 13
// 110.889 us; speedup vs baseline: 1.1383x; 1.0208x over previous
//
#include <hip/hip_runtime.h>
#include <hip/hip_bf16.h>

#define M_ 501
#define T_ 512
#define DT_ 0.01f

typedef __attribute__((ext_vector_type(8))) __bf16 bf16x8;
typedef __attribute__((ext_vector_type(4))) float f32x4;

static __device__ __forceinline__ unsigned int pack2(float a, float b) {
    __hip_bfloat16 ha = __float2bfloat16(a);
    __hip_bfloat16 hb = __float2bfloat16(b);
    unsigned short ua = __builtin_bit_cast(unsigned short, ha);
    unsigned short ub = __builtin_bit_cast(unsigned short, hb);
    return (unsigned int)ua | ((unsigned int)ub << 16);
}

// ---------------- P2: W1comb (1024 x 384) pre-swizzled into MFMA fragment order
// [((kg*24 + nt)*64 + lane)*8 + e] : k = kg*32 + (lane>>4)*8 + e, n = nt*16 + (lane&15)
__global__ void build_w(const float* __restrict__ Ew1, const float* __restrict__ bw1,
                        const float* __restrict__ nw1, __hip_bfloat16* __restrict__ Wswz) {
    int idx = blockIdx.x * 256 + threadIdx.x;       // total 32*24*64*8 = 393216
    if (idx >= 32 * 24 * 64 * 8) return;
    int e  = idx & 7;
    int l  = (idx >> 3) & 63;
    int t  = idx >> 9;
    int nt = t % 24, k0 = t / 24;
    int k  = k0 * 32 + ((l >> 4) << 3) + e;
    int n  = nt * 16 + (l & 15);
    float v = 0.f;
    if (n < 128)      { if (k < 2*M_)             v = Ew1[k * 128 + n]; }
    else if (n < 256) { if (k < 2*M_)             v = bw1[k * 128 + (n - 128)]; }
    else              { if (k >= M_ && k < 2*M_)  v = nw1[(k - M_) * 128 + (n - 256)]; }
    Wswz[idx] = __float2bfloat16(v);
}

// ---------------- Fused: MLP GEMM + epilogue + scan, 64 rows/block -----------
// 512 thr (8 waves), grid 512 (2 blocks/CU target: VGPR<=128, LDS ~20KB).
// KEY FIX vs R8-R12: per chunk, W loads are issued BEFORE the staging loads.
// vmcnt retires in issue order, so waiting on W no longer transitively waits
// the ~900cy HBM staging loads. W is prefetched 1 kg ahead (wcur/wnxt).
// After the GEMM epilogue the SAME block scans its 64 rows (scalars via LDS).
__global__ __launch_bounds__(512, 4) void fused_all(
    const float* __restrict__ E, const float* __restrict__ nu,
    const __hip_bfloat16* __restrict__ Wswz,
    const float* __restrict__ Eb1, const float* __restrict__ bb1, const float* __restrict__ nb1,
    const float* __restrict__ Ew2, const float* __restrict__ bw2, const float* __restrict__ nw2,
    const float* __restrict__ Eb2, const float* __restrict__ bb2, const float* __restrict__ nb2,
    const float* __restrict__ e, const float* __restrict__ ed,
    float* __restrict__ stress, float* __restrict__ xiout, int B)
{
    const int tid = threadIdx.x;
    const int wid = tid >> 6, l = tid & 63;
    const int c = l & 15, g = l >> 4;
    const int brow = blockIdx.x * 64;

    __shared__ __align__(16) unsigned char sAraw[2][64 * 128];    // 16 KB
    __shared__ float cb1[384], cw2[384];
    __shared__ float lds_s[3][64];

    if (tid < 384) {
        int n = tid;
        cb1[n] = (n < 128) ? Eb1[n] : (n < 256) ? bb1[n - 128] : nb1[n - 256];
        cw2[n] = (n < 128) ? Ew2[n] : (n < 256) ? bw2[n - 128] : nw2[n - 256];
    }
    if (tid < 192) ((float*)lds_s)[tid] = 0.f;

    // ---- staging machinery: 1 item/thread/chunk (8 elems) ----
    f32x4 q0, q1, q2; int ofs;
    const int sr = tid >> 3, su = tid & 7;           // row 0..63, col-octet 0..7
    const size_t rb = (size_t)(brow + sr) * M_;
    auto stage_load = [&](int ch) {
        int cu = ch * 8 + su;
        bool slow = (cu == 62) | (cu >= 124);
        if (!slow) {
            const float* src = (cu < 62) ? E : nu;
            int off = (cu < 62) ? cu * 8 : cu * 8 - M_;
            size_t s = rb + (size_t)off;
            ofs = (int)(s & 3);
            const f32x4* p = (const f32x4*)(src + (s & ~(size_t)3));
            q0 = p[0]; q1 = p[1]; q2 = p[2];
        } else {
            int kb = cu * 8;
            auto ldx = [&](int k) -> float {
                return (k < M_) ? E[rb + k] : ((k < 2 * M_) ? nu[rb + k - M_] : 0.f);
            };
            q0 = (f32x4){ldx(kb+0), ldx(kb+1), ldx(kb+2), ldx(kb+3)};
            q1 = (f32x4){ldx(kb+4), ldx(kb+5), ldx(kb+6), ldx(kb+7)};
            q2 = (f32x4){0.f, 0.f, 0.f, 0.f};
            ofs = 0;
        }
    };
    auto stage_finish = [&](int nbuf) {
        asm volatile("" : "+v"(q0), "+v"(q1), "+v"(q2));   // first use: wait lands here
        float g0=q0[0], g1=q0[1], g2=q0[2], g3=q0[3],
              g4=q1[0], g5=q1[1], g6=q1[2], g7=q1[3],
              g8=q2[0], g9=q2[1], g10=q2[2];
        const bool o2 = (ofs & 2) != 0, o1 = (ofs & 1) != 0;
        float u0 = o2?g2:g0, u1 = o2?g3:g1, u2 = o2?g4:g2, u3 = o2?g5:g3,
              u4 = o2?g6:g4, u5 = o2?g7:g5, u6 = o2?g8:g6, u7 = o2?g9:g7,
              u8 = o2?g10:g8;
        float f0 = o1?u1:u0, f1 = o1?u2:u1, f2 = o1?u3:u2, f3 = o1?u4:u3,
              f4 = o1?u5:u4, f5 = o1?u6:u5, f6 = o1?u7:u6, f7 = o1?u8:u7;
        uint4 vv;
        vv.x = pack2(f0, f1); vv.y = pack2(f2, f3);
        vv.z = pack2(f4, f5); vv.w = pack2(f6, f7);
        unsigned bo = ((unsigned)sr << 7) + ((((unsigned)su) << 4) ^ (((unsigned)(sr & 7)) << 4));
        *(uint4*)(sAraw[nbuf] + bo) = vv;
    };

    const bf16x8* wbase = (const bf16x8*)Wswz;
    auto loadW3 = [&](bf16x8 (&w)[3], int kg) {
        #pragma unroll
        for (int nt = 0; nt < 3; ++nt)
            w[nt] = wbase[(size_t)(kg * 24 + wid * 3 + nt) * 64 + l];
    };

    f32x4 acc[4][3];
    #pragma unroll
    for (int mi = 0; mi < 4; mi++)
        #pragma unroll
        for (int nt = 0; nt < 3; nt++) acc[mi][nt] = (f32x4){0.f, 0.f, 0.f, 0.f};
    bf16x8 wcur[3], wnxt[3], af[4];

    auto readAF = [&](int buf, int kk) {
        #pragma unroll
        for (int mi = 0; mi < 4; ++mi) {
            int row = c + mi * 16;
            unsigned bo = ((unsigned)row << 7) +
                ((((unsigned)kk << 6) + ((unsigned)g << 4)) ^ (((unsigned)(row & 7)) << 4));
            af[mi] = *(const bf16x8*)(sAraw[buf] + bo);
        }
    };
    auto M12 = [&](bf16x8 (&w)[3]) {
        #pragma unroll
        for (int nt = 0; nt < 3; ++nt)
            #pragma unroll
            for (int mi = 0; mi < 4; ++mi)
                acc[mi][nt] = __builtin_amdgcn_mfma_f32_16x16x32_bf16(w[nt], af[mi], acc[mi][nt], 0, 0, 0);
    };

    // ---- prologue: stage chunk 0 (issued first), W kg=0 after -> W wait is cheap
    stage_load(0);
    loadW3(wcur, 0);
    stage_finish(0);                                 // waits stage only (FIFO: older)
    __syncthreads();

    // ---- chunk loop: 16 chunks of BK=64 (2 kg each) ----
    for (int ch = 0; ch < 16; ++ch) {
        const int buf = ch & 1;
        const int kg = ch * 2;
        loadW3(wnxt, kg + 1);                        // W FIRST...
        if (ch < 15) stage_load(ch + 1);             // ...stage AFTER (FIFO unchained)
        readAF(buf, 0); M12(wcur);
        if (ch < 15) loadW3(wcur, kg + 2);           // next chunk's kg0 (in flight over barrier)
        readAF(buf, 1); M12(wnxt);
        if (ch < 15) stage_finish(buf ^ 1);          // waits stage (W already retired/older)
        __syncthreads();
    }

    // ---- epilogue: hidden-units on reg axis -> cheap reduce ----
    float bv[12], wv[12];
    #pragma unroll
    for (int nt = 0; nt < 3; ++nt)
        #pragma unroll
        for (int r = 0; r < 4; ++r) {
            int nidx = (wid * 3 + nt) * 16 + g * 4 + r;
            bv[nt * 4 + r] = cb1[nidx];
            wv[nt * 4 + r] = cw2[nidx];
        }
    const int m_first = (wid * 3) >> 3, m_last = (wid * 3 + 2) >> 3;

    #pragma unroll
    for (int mi = 0; mi < 4; ++mi) {
        float s0 = 0.f, s1 = 0.f, s2 = 0.f;
        #pragma unroll
        for (int nt = 0; nt < 3; ++nt) {
            float p = 0.f;
            #pragma unroll
            for (int r = 0; r < 4; ++r) {
                float x = acc[mi][nt][r] + bv[nt * 4 + r];
                float h = fmaxf(x, 0.f) + __logf(1.f + __expf(-fabsf(x)));
                p += h * wv[nt * 4 + r];
            }
            int m = (wid * 3 + nt) >> 3;
            if (m == 0) s0 += p; else if (m == 1) s1 += p; else s2 += p;
        }
        auto red = [&](float v, int m) {
            v += __shfl_xor(v, 16);
            v += __shfl_xor(v, 32);
            if (l < 16) atomicAdd(&lds_s[m][mi * 16 + l], v);
        };
        if (m_first == 0) red(s0, 0);
        if (m_first <= 1 && m_last >= 1) red(s1, 1);
        if (m_last == 2) red(s2, 2);
    }
    __syncthreads();

    // ---- finalize per-row scalars in LDS ----
    if (tid < 64) {
        float s0 = lds_s[0][tid], s1 = lds_s[1][tid], s2 = lds_s[2][tid];
        lds_s[0][tid] = __expf(s0 + Eb2[0]);                      // Emod
        float mb = s1 + bb2[0];
        lds_s[1][tid] = mb * mb * (1.f / 40000.f);                // beta
        float mn = s2 + nb2[0];
        lds_s[2][tid] = __expf(mn * mn * (1.f / 40000.f));        // nuv
    }
    __syncthreads();

    // ---- fused scan: wave wid handles rows wid*8 .. wid*8+7 ----
    for (int i = 0; i < 8; ++i) {
        const int rr = wid * 8 + i;
        const int b = brow + rr;
        float Em = lds_s[0][rr], bt = lds_s[1][rr], nv = lds_s[2][rr];
        float cc = DT_ * bt;
        float a  = 1.f - cc;

        size_t base = (size_t)b * T_ + (size_t)l * 8;
        float4 e0 = *(const float4*)(e + base),  e1 = *(const float4*)(e + base + 4);
        float4 d0 = *(const float4*)(ed + base), d1 = *(const float4*)(ed + base + 4);
        float ev[8] = {e0.x, e0.y, e0.z, e0.w, e1.x, e1.y, e1.z, e1.w};
        float dv[8] = {d0.x, d0.y, d0.z, d0.w, d1.x, d1.y, d1.z, d1.w};

        float S = 0.f;
        #pragma unroll
        for (int j = 0; j < 8; j++) S = a * S + ev[j];
        float a2 = a * a, a4 = a2 * a2, A = a4 * a4;

        #pragma unroll
        for (int d = 1; d < 64; d <<= 1) {
            float Su = __shfl_up(S, d);
            float Au = __shfl_up(A, d);
            if (l >= d) { S = Su * A + S; A = Au * A; }
        }
        float Sp = __shfl_up(S, 1);
        float xi = (l == 0) ? 0.f : cc * Sp;

        float st[8], xo[8];
        #pragma unroll
        for (int j = 0; j < 8; j++) {
            xo[j] = xi;
            float qd = ev[j] - xi;
            st[j] = Em * ev[j] + qd + nv * dv[j];
            xi = xi + cc * qd;
        }
        *(float4*)(stress + base)     = (float4){st[0], st[1], st[2], st[3]};
        *(float4*)(stress + base + 4) = (float4){st[4], st[5], st[6], st[7]};
        *(float4*)(xiout + base)      = (float4){xo[0], xo[1], xo[2], xo[3]};
        *(float4*)(xiout + base + 4)  = (float4){xo[4], xo[5], xo[6], xo[7]};
    }
}

extern "C" void kernel_launch(void* const* d_in, const int* in_sizes, int n_in,
                              void* d_out, int out_size, void* d_ws, size_t ws_size,
                              hipStream_t stream) {
    const float* e   = (const float*)d_in[0];
    const float* ed  = (const float*)d_in[1];
    const float* E   = (const float*)d_in[2];
    const float* nu  = (const float*)d_in[3];
    const float* Ew1 = (const float*)d_in[4];
    const float* Eb1 = (const float*)d_in[5];
    const float* Ew2 = (const float*)d_in[6];
    const float* Eb2 = (const float*)d_in[7];
    const float* nw1 = (const float*)d_in[8];
    const float* nb1 = (const float*)d_in[9];
    const float* nw2 = (const float*)d_in[10];
    const float* nb2 = (const float*)d_in[11];
    const float* bw1 = (const float*)d_in[12];
    const float* bb1 = (const float*)d_in[13];
    const float* bw2 = (const float*)d_in[14];
    const float* bb2 = (const float*)d_in[15];

    int B = in_sizes[2] / M_;                       // 32768

    char* ws = (char*)d_ws;
    __hip_bfloat16* Wswz = (__hip_bfloat16*)ws;     // 786432 bytes

    float* stress = (float*)d_out;
    float* xiout  = stress + (size_t)B * T_;

    build_w<<<(1024 * 384 + 255) / 256, 256, 0, stream>>>(Ew1, bw1, nw1, Wswz);
    fused_all<<<B / 64, 512, 0, stream>>>(E, nu, Wswz, Eb1, bb1, nb1,
                                          Ew2, bw2, nw2, Eb2, bb2, nb2,
                                          e, ed, stress, xiout, B);
}